// Round 1
// baseline (115.709 us; speedup 1.0000x reference)
//
#include <hip/hip_runtime.h>

typedef __bf16 bf16x8 __attribute__((ext_vector_type(8)));
typedef float f32x4 __attribute__((ext_vector_type(4)));
typedef unsigned int uint4v __attribute__((ext_vector_type(4)));
typedef unsigned short ushort_t;
typedef unsigned int uint_t;

#define RS 0.08838834764831845f   // 1/sqrt(128)

__device__ __forceinline__ ushort_t f2bf(float f) {
    uint_t u = __float_as_uint(f);
    u += 0x7FFFu + ((u >> 16) & 1u);   // round-to-nearest-even
    return (ushort_t)(u >> 16);
}
__device__ __forceinline__ uint_t pack2(float a, float b) {
    return (uint_t)f2bf(a) | ((uint_t)f2bf(b) << 16);
}
union U4B8 { uint4v u; bf16x8 b; };
__device__ __forceinline__ bf16x8 as_bf(uint4v u) { U4B8 x; x.u = u; return x.b; }

// padded xs frag addressing: frag stride 1072B (67x16), phase stride 272B (17x16)
__device__ __forceinline__ int xfrag(int f, int lane) {
    return f * 1072 + ((lane >> 4) * 272) + ((lane & 15) * 16);
}

// async global->LDS, 16B/lane; LDS dest = wave-uniform base + lane*16 (m104)
__device__ __forceinline__ void gload16(const void* g, void* l) {
    __builtin_amdgcn_global_load_lds(
        (const __attribute__((address_space(1))) void*)g,
        (__attribute__((address_space(3))) void*)l, 16, 0, 0);
}

// ---------------------------------------------------------------------------
// Prep (one dispatch, 576 blocks). Blocks 0..63: K'[m]=keys[m]@Wq via
// 2-way e-split over 256 threads + LDS reduce, plus cb[m]=bq.keys[m].
// Blocks 64..575: swizzle ops -> bf16 B-frag order.
// NEW layout: each (m, dh) half-tile contiguous (16 KB) so main_kernel can
// stage it linearly with global_load_lds:
//   h = m*2048 + (dt>>2)*1024 + ks*256 + (dt&3)*64 + L
// frag(m,ks,dt): lane L holds ops[m][d=dt*16+(L&15)][e=ks*32+(L>>4)*8+j]
// ---------------------------------------------------------------------------
__global__ __launch_bounds__(256) void prep_kernel(
    const float* __restrict__ ops, const float* __restrict__ keys,
    const float* __restrict__ Wq, const float* __restrict__ bq,
    uint4v* __restrict__ ops_sw, ushort_t* __restrict__ kp_sw,
    float* __restrict__ cb)
{
    const int tid = threadIdx.x;
    const int b = blockIdx.x;
    if (b >= 64) {
        int g = (b - 64) * 256 + tid;     // [0, 131072)
        int L = g & 63, dt = (g >> 6) & 7, ks = (g >> 9) & 3, m = g >> 11;
        int d = dt * 16 + (L & 15);
        int e0 = ks * 32 + ((L >> 4) << 3);
        const float4* s = (const float4*)(ops + (((size_t)(m * 128 + d)) << 7) + e0);
        float4 v0 = s[0], v1 = s[1];
        uint4v o = { pack2(v0.x, v0.y), pack2(v0.z, v0.w),
                     pack2(v1.x, v1.y), pack2(v1.z, v1.w) };
        int h = m * 2048 + (dt >> 2) * 1024 + ks * 256 + (dt & 3) * 64 + L;
        ops_sw[h] = o;
    } else {
        __shared__ float red[256];
        const int m = b;
        const int d = tid & 127, eh = tid >> 7;
        const float* kr = keys + m * 128 + eh * 64;
        const float* wc = Wq + (size_t)(eh * 64) * 128 + d;
        float acc = 0.f;
        #pragma unroll 8
        for (int e = 0; e < 64; ++e)
            acc = fmaf(kr[e], wc[(size_t)e * 128], acc);
        red[tid] = acc;
        __syncthreads();
        if (tid < 128) {
            float v = red[tid] + red[tid + 128];
            int ki = d >> 5, qq = (d >> 3) & 3, j = d & 7;
            kp_sw[((((ki * 4 + (m >> 4)) * 64) + (qq * 16 + (m & 15))) << 3) | j] = f2bf(v);
        } else if (tid >= 192) {
            int lane = tid - 192;
            float p = keys[m * 128 + lane] * bq[lane]
                    + keys[m * 128 + 64 + lane] * bq[64 + lane];
            #pragma unroll
            for (int off = 1; off < 64; off <<= 1) p += __shfl_xor(p, off);
            if (lane == 0) cb[m] = p;
        }
    }
}

// ---------------------------------------------------------------------------
// Main: 256 blocks = 128 token-tiles x 2 d-halves, 512 threads (8 waves).
// Block = 128 t x 64 d x ALL 64 slots. Waves: (tg = w>>2) token-64-group,
// (dtp = w&3) d-16-tile -> every B byte feeds 128 tokens (2x reuse vs R9),
// halving per-CU L2 pull per FLOP.
// B staged per slot-PAIR into LDS via global_load_lds, double-buffered
// (2 x 32 KB). 2-phase pipeline: issue stage(p+1) -> compute pair p ->
// __syncthreads (its vmcnt(0) drain lands ~1000cy after issue; L2-hit
// latency ~300cy -> free). MFMA pipe becomes the critical path.
// ---------------------------------------------------------------------------
__global__ __launch_bounds__(512, 2) void main_kernel(
    const float* __restrict__ x, const float* __restrict__ cb,
    const ushort_t* __restrict__ kp_sw, const uint4v* __restrict__ ops_sw,
    float* __restrict__ out)
{
    __shared__ __align__(16) unsigned char xs[34304];   // 32 padded A-frags
    __shared__ float attn_f[64 * 132];                  // [slot][token(128)+pad]
    __shared__ __align__(16) uint4v bb[2][2048];        // 2 x 32KB B pair-buffers

    const int tid = threadIdx.x;          // 0..511
    const int lane = tid & 63;
    const int w = tid >> 6;               // wave 0..7
    const int q = lane >> 4;
    const int l15 = lane & 15;
    const int tb = blockIdx.x >> 1;       // token tile 0..127
    const int dh = blockIdx.x & 1;
    const int t0 = tb * 128;
    const int dtp = w & 3;                // d-16-tile within half
    const int tg = w >> 2;                // token 64-group (phase 3)

    // ---- Phase 1: stage x tile (128x128) -> bf16 A-frag order, bank-padded
    {
        const float4* x4 = (const float4*)(x + (size_t)t0 * 128);
        #pragma unroll
        for (int it = 0; it < 4; ++it) {
            int i = it * 512 + tid;
            int t = i >> 4, kc = i & 15;
            float4 a = x4[t * 32 + kc * 2];
            float4 b2 = x4[t * 32 + kc * 2 + 1];
            uint4v o = { pack2(a.x, a.y), pack2(a.z, a.w),
                         pack2(b2.x, b2.y), pack2(b2.z, b2.w) };
            *(uint4v*)(xs + ((t >> 4) * 4 + (kc >> 2)) * 1072
                          + (kc & 3) * 272 + (t & 15) * 16) = o;
        }
    }
    __syncthreads();

    // ---- Phase 2: attention (wave w owns tokens w*16..w*16+15), all 64 slots
    {
        f32x4 L0 = {0,0,0,0}, L1 = {0,0,0,0}, L2 = {0,0,0,0}, L3 = {0,0,0,0};
        const uint4v* kpf = (const uint4v*)kp_sw;
        #pragma unroll
        for (int ki = 0; ki < 4; ++ki) {
            bf16x8 a = *(const bf16x8*)(xs + xfrag(w * 4 + ki, lane));
            L0 = __builtin_amdgcn_mfma_f32_16x16x32_bf16(a, as_bf(kpf[(ki*4+0)*64 + lane]), L0, 0,0,0);
            L1 = __builtin_amdgcn_mfma_f32_16x16x32_bf16(a, as_bf(kpf[(ki*4+1)*64 + lane]), L1, 0,0,0);
            L2 = __builtin_amdgcn_mfma_f32_16x16x32_bf16(a, as_bf(kpf[(ki*4+2)*64 + lane]), L2, 0,0,0);
            L3 = __builtin_amdgcn_mfma_f32_16x16x32_bf16(a, as_bf(kpf[(ki*4+3)*64 + lane]), L3, 0,0,0);
        }
        float c0 = cb[l15], c1 = cb[16 + l15], c2 = cb[32 + l15], c3 = cb[48 + l15];
        #pragma unroll
        for (int r = 0; r < 4; ++r) {
            float v0 = (L0[r] + c0) * RS;
            float v1 = (L1[r] + c1) * RS;
            float v2 = (L2[r] + c2) * RS;
            float v3 = (L3[r] + c3) * RS;
            float mx = fmaxf(fmaxf(v0, v1), fmaxf(v2, v3));
            #pragma unroll
            for (int off = 1; off < 16; off <<= 1) mx = fmaxf(mx, __shfl_xor(mx, off));
            float e0 = __expf(v0 - mx), e1 = __expf(v1 - mx),
                  e2 = __expf(v2 - mx), e3 = __expf(v3 - mx);
            float sm = e0 + e1 + e2 + e3;
            #pragma unroll
            for (int off = 1; off < 16; off <<= 1) sm += __shfl_xor(sm, off);
            float inv = 1.0f / sm;
            int t = w * 16 + q * 4 + r;
            attn_f[(     l15) * 132 + t] = e0 * inv;
            attn_f[(16 + l15) * 132 + t] = e1 * inv;
            attn_f[(32 + l15) * 132 + t] = e2 * inv;
            attn_f[(48 + l15) * 132 + t] = e3 * inv;
        }
    }

    // ---- A-frags for this wave's 64-token group, kept all slot-loop
    bf16x8 A[4][4];
    #pragma unroll
    for (int tf = 0; tf < 4; ++tf)
        #pragma unroll
        for (int ki = 0; ki < 4; ++ki)
            A[tf][ki] = *(const bf16x8*)(xs + xfrag(tg * 16 + tf * 4 + ki, lane));

    // ---- stage one slot-pair (32 KB) into bb[buf]: 4 x global_load_lds /thread
    const int sb = w * 64 + lane;  // == tid, lane-varying global offset
    auto stage = [&](int pair, int buf) {
        #pragma unroll
        for (int j = 0; j < 4; ++j) {
            int slot = pair * 2 + (j >> 1);
            const uint4v* g = ops_sw + ((size_t)(slot * 2 + dh) << 10)
                            + (j & 1) * 512 + sb;
            gload16((const void*)g, (void*)&bb[buf][j * 512 + (w << 6)]);
        }
    };

    stage(0, 0);
    __syncthreads();   // attn_f ready + pair-0 stage drained (vmcnt(0) @ barrier)

    // ---- Phase 3: 32 pairs of slots, 2-phase double-buffered pipeline
    f32x4 C[4] = {};
    #pragma unroll 2
    for (int p = 0; p < 32; ++p) {
        if (p < 31) stage(p + 1, (p + 1) & 1);      // issue-early
        const uint4v* bbuf = &bb[p & 1][0];
        #pragma unroll
        for (int sl = 0; sl < 2; ++sl) {
            const int m = p * 2 + sl;
            f32x4 S[4] = {};
            #pragma unroll
            for (int ki = 0; ki < 4; ++ki) {
                bf16x8 bfrag = as_bf(bbuf[sl * 1024 + ki * 256 + dtp * 64 + lane]);
                #pragma unroll
                for (int tf = 0; tf < 4; ++tf)
                    S[tf] = __builtin_amdgcn_mfma_f32_16x16x32_bf16(A[tf][ki], bfrag, S[tf], 0,0,0);
            }
            #pragma unroll
            for (int tf = 0; tf < 4; ++tf) {
                f32x4 af = *(const f32x4*)&attn_f[m * 132 + tg * 64 + tf * 16 + q * 4];
                #pragma unroll
                for (int r = 0; r < 4; ++r)
                    C[tf][r] = fmaf(af[r], S[tf][r], C[tf][r]);
            }
        }
        __syncthreads();   // drains stage(p+1) loads (~1000cy after issue) + swap
    }

    // ---- Epilogue: direct stores (complete sums; no atomics)
    float* op = out + (size_t)t0 * 128 + dh * 64 + dtp * 16 + l15;
    #pragma unroll
    for (int tf = 0; tf < 4; ++tf)
        #pragma unroll
        for (int r = 0; r < 4; ++r)
            op[(size_t)(tg * 64 + tf * 16 + q * 4 + r) * 128] = C[tf][r];
}

// ---------------------------------------------------------------------------
extern "C" void kernel_launch(void* const* d_in, const int* in_sizes, int n_in,
                              void* d_out, int out_size, void* d_ws, size_t ws_size,
                              hipStream_t stream)
{
    const float* x    = (const float*)d_in[0];   // (4,4096,128)
    const float* keys = (const float*)d_in[1];   // (64,128)
    const float* ops  = (const float*)d_in[2];   // (64,128,128)
    const float* Wq   = (const float*)d_in[3];   // (128,128)
    const float* bq   = (const float*)d_in[4];   // (128,)
    float* out = (float*)d_out;

    char* ws = (char*)d_ws;
    uint4v*   ops_sw = (uint4v*)ws;                        // 2 MB
    ushort_t* kp_sw  = (ushort_t*)(ws + 2097152);          // 16 KB
    float*    cb     = (float*)(ws + 2097152 + 16384);     // 256 B

    prep_kernel<<<576, 256, 0, stream>>>(ops, keys, Wq, bq, ops_sw, kp_sw, cb);
    main_kernel<<<256, 512, 0, stream>>>(x, cb, kp_sw, ops_sw, out);
}

// Round 2
// 104.681 us; speedup vs baseline: 1.1054x; 1.1054x over previous
//
#include <hip/hip_runtime.h>

typedef __bf16 bf16x8 __attribute__((ext_vector_type(8)));
typedef float f32x4 __attribute__((ext_vector_type(4)));
typedef unsigned int uint4v __attribute__((ext_vector_type(4)));
typedef unsigned short ushort_t;
typedef unsigned int uint_t;

#define RS 0.08838834764831845f   // 1/sqrt(128)

__device__ __forceinline__ ushort_t f2bf(float f) {
    uint_t u = __float_as_uint(f);
    u += 0x7FFFu + ((u >> 16) & 1u);   // round-to-nearest-even
    return (ushort_t)(u >> 16);
}
__device__ __forceinline__ uint_t pack2(float a, float b) {
    return (uint_t)f2bf(a) | ((uint_t)f2bf(b) << 16);
}
union U4B8 { uint4v u; bf16x8 b; };
__device__ __forceinline__ bf16x8 as_bf(uint4v u) { U4B8 x; x.u = u; return x.b; }

// padded xs frag addressing: frag stride 1072B (67x16), phase stride 272B (17x16)
__device__ __forceinline__ int xfrag(int f, int lane) {
    return f * 1072 + ((lane >> 4) * 272) + ((lane & 15) * 16);
}

// async global->LDS, 16B/lane; LDS dest = wave-uniform base + lane*16 (m104)
__device__ __forceinline__ void gload16(const void* g, void* l) {
    __builtin_amdgcn_global_load_lds(
        (const __attribute__((address_space(1))) void*)g,
        (__attribute__((address_space(3))) void*)l, 16, 0, 0);
}

// ---------------------------------------------------------------------------
// Prep (one dispatch, 576 blocks). Blocks 0..63: K'[m]=keys[m]@Wq via
// 2-way e-split over 256 threads + LDS reduce, plus cb[m]=bq.keys[m].
// Blocks 64..575: swizzle ops -> bf16 B-frag order. Each (m, dh) half-tile
// contiguous (16 KB) so main_kernel can stage it linearly:
//   h = m*2048 + (dt>>2)*1024 + ks*256 + (dt&3)*64 + L
// frag(m,ks,dt): lane L holds ops[m][d=dt*16+(L&15)][e=ks*32+(L>>4)*8+j]
// ---------------------------------------------------------------------------
__global__ __launch_bounds__(256) void prep_kernel(
    const float* __restrict__ ops, const float* __restrict__ keys,
    const float* __restrict__ Wq, const float* __restrict__ bq,
    uint4v* __restrict__ ops_sw, ushort_t* __restrict__ kp_sw,
    float* __restrict__ cb)
{
    const int tid = threadIdx.x;
    const int b = blockIdx.x;
    if (b >= 64) {
        int g = (b - 64) * 256 + tid;     // [0, 131072)
        int L = g & 63, dt = (g >> 6) & 7, ks = (g >> 9) & 3, m = g >> 11;
        int d = dt * 16 + (L & 15);
        int e0 = ks * 32 + ((L >> 4) << 3);
        const float4* s = (const float4*)(ops + (((size_t)(m * 128 + d)) << 7) + e0);
        float4 v0 = s[0], v1 = s[1];
        uint4v o = { pack2(v0.x, v0.y), pack2(v0.z, v0.w),
                     pack2(v1.x, v1.y), pack2(v1.z, v1.w) };
        int h = m * 2048 + (dt >> 2) * 1024 + ks * 256 + (dt & 3) * 64 + L;
        ops_sw[h] = o;
    } else {
        __shared__ float red[256];
        const int m = b;
        const int d = tid & 127, eh = tid >> 7;
        const float* kr = keys + m * 128 + eh * 64;
        const float* wc = Wq + (size_t)(eh * 64) * 128 + d;
        float acc = 0.f;
        #pragma unroll 8
        for (int e = 0; e < 64; ++e)
            acc = fmaf(kr[e], wc[(size_t)e * 128], acc);
        red[tid] = acc;
        __syncthreads();
        if (tid < 128) {
            float v = red[tid] + red[tid + 128];
            int ki = d >> 5, qq = (d >> 3) & 3, j = d & 7;
            kp_sw[((((ki * 4 + (m >> 4)) * 64) + (qq * 16 + (m & 15))) << 3) | j] = f2bf(v);
        } else if (tid >= 192) {
            int lane = tid - 192;
            float p = keys[m * 128 + lane] * bq[lane]
                    + keys[m * 128 + 64 + lane] * bq[64 + lane];
            #pragma unroll
            for (int off = 1; off < 64; off <<= 1) p += __shfl_xor(p, off);
            if (lane == 0) cb[m] = p;
        }
    }
}

// ---------------------------------------------------------------------------
// Main: 256 blocks (1/CU), 512 threads (8 waves). Block = 128 t x 64 d x all
// 64 slots; wave = 64 t (tg=w>>2) x 16 d (dtp=w&3). Every B byte feeds 128
// tokens (2x reuse of R9).
// R11 fix over R10: counted-vmcnt pipeline (T4). 3-deep 32 KB slot-pair LDS
// ring; per iter: issue stage(p+1) -> s_waitcnt vmcnt(4) (stage(p+1) stays in
// flight ACROSS the barrier) -> raw s_barrier -> MFMA pair p. No vmcnt(0)
// drain in the loop; stage slack = one pair-compute (~1240 cy/CU) >> L2
// latency (~300 cy). xs (A-staging) is dead after A-frag reg load and is
// aliased under the ring -> 129 KB LDS, 1 block/CU, all 256 CUs occupied.
// ---------------------------------------------------------------------------
__global__ __launch_bounds__(512, 2) void main_kernel(
    const float* __restrict__ x, const float* __restrict__ cb,
    const ushort_t* __restrict__ kp_sw, const uint4v* __restrict__ ops_sw,
    float* __restrict__ out)
{
    // LDS plan: [0, 33792)         attn_f  f32[64][132]
    //           [33792, 132096)    3 x 32 KB pair buffers (ring)
    //           xs (34304 B A-frag staging) aliased at 33792, dead pre-ring
    __shared__ __align__(16) unsigned char lds[132096];
    float* attn_f = (float*)lds;
    unsigned char* xs = lds + 33792;
    uint4v* bb = (uint4v*)(lds + 33792);   // 3 * 2048 uint4v

    const int tid = threadIdx.x;          // 0..511
    const int lane = tid & 63;
    const int w = tid >> 6;               // wave 0..7
    const int q = lane >> 4;
    const int l15 = lane & 15;
    const int tb = blockIdx.x >> 1;       // token tile 0..127
    const int dh = blockIdx.x & 1;
    const int t0 = tb * 128;
    const int dtp = w & 3;                // d-16-tile within half
    const int tg = w >> 2;                // token 64-group (phase 3)

    // ---- Phase 1: stage x tile (128x128) -> bf16 A-frag order, bank-padded
    {
        const float4* x4 = (const float4*)(x + (size_t)t0 * 128);
        #pragma unroll
        for (int it = 0; it < 4; ++it) {
            int i = it * 512 + tid;
            int t = i >> 4, kc = i & 15;
            float4 a = x4[t * 32 + kc * 2];
            float4 b2 = x4[t * 32 + kc * 2 + 1];
            uint4v o = { pack2(a.x, a.y), pack2(a.z, a.w),
                         pack2(b2.x, b2.y), pack2(b2.z, b2.w) };
            *(uint4v*)(xs + ((t >> 4) * 4 + (kc >> 2)) * 1072
                          + (kc & 3) * 272 + (t & 15) * 16) = o;
        }
    }
    __syncthreads();

    // ---- Phase 2: attention (wave w owns tokens w*16..w*16+15), all 64 slots
    {
        f32x4 L0 = {0,0,0,0}, L1 = {0,0,0,0}, L2 = {0,0,0,0}, L3 = {0,0,0,0};
        const uint4v* kpf = (const uint4v*)kp_sw;
        #pragma unroll
        for (int ki = 0; ki < 4; ++ki) {
            bf16x8 a = *(const bf16x8*)(xs + xfrag(w * 4 + ki, lane));
            L0 = __builtin_amdgcn_mfma_f32_16x16x32_bf16(a, as_bf(kpf[(ki*4+0)*64 + lane]), L0, 0,0,0);
            L1 = __builtin_amdgcn_mfma_f32_16x16x32_bf16(a, as_bf(kpf[(ki*4+1)*64 + lane]), L1, 0,0,0);
            L2 = __builtin_amdgcn_mfma_f32_16x16x32_bf16(a, as_bf(kpf[(ki*4+2)*64 + lane]), L2, 0,0,0);
            L3 = __builtin_amdgcn_mfma_f32_16x16x32_bf16(a, as_bf(kpf[(ki*4+3)*64 + lane]), L3, 0,0,0);
        }
        float c0 = cb[l15], c1 = cb[16 + l15], c2 = cb[32 + l15], c3 = cb[48 + l15];
        #pragma unroll
        for (int r = 0; r < 4; ++r) {
            float v0 = (L0[r] + c0) * RS;
            float v1 = (L1[r] + c1) * RS;
            float v2 = (L2[r] + c2) * RS;
            float v3 = (L3[r] + c3) * RS;
            float mx = fmaxf(fmaxf(v0, v1), fmaxf(v2, v3));
            #pragma unroll
            for (int off = 1; off < 16; off <<= 1) mx = fmaxf(mx, __shfl_xor(mx, off));
            float e0 = __expf(v0 - mx), e1 = __expf(v1 - mx),
                  e2 = __expf(v2 - mx), e3 = __expf(v3 - mx);
            float sm = e0 + e1 + e2 + e3;
            #pragma unroll
            for (int off = 1; off < 16; off <<= 1) sm += __shfl_xor(sm, off);
            float inv = 1.0f / sm;
            int t = w * 16 + q * 4 + r;
            attn_f[(     l15) * 132 + t] = e0 * inv;
            attn_f[(16 + l15) * 132 + t] = e1 * inv;
            attn_f[(32 + l15) * 132 + t] = e2 * inv;
            attn_f[(48 + l15) * 132 + t] = e3 * inv;
        }
    }

    // ---- A-frags for this wave's 64-token group, kept all slot-loop
    bf16x8 A[4][4];
    #pragma unroll
    for (int tf = 0; tf < 4; ++tf)
        #pragma unroll
        for (int ki = 0; ki < 4; ++ki)
            A[tf][ki] = *(const bf16x8*)(xs + xfrag(tg * 16 + tf * 4 + ki, lane));

    // Full drain + barrier: xs reads done in ALL waves, attn_f published,
    // vmcnt==0 baseline before the counted pipeline starts. xs is now dead.
    __syncthreads();

    // ---- stage one slot-pair (32 KB) into ring buf b: 4 gload_lds / thread
    // dest element = j*512 + w*64 (+lane by HW); matching source element so
    // compute reads bb[b][sl*1024 + ki*256 + dtp*64 + lane].
    auto stage = [&](int pair, int b) {
        uint4v* dst = bb + b * 2048 + w * 64;
        const uint4v* src = ops_sw + (size_t)pair * 4096 + dh * 1024 + w * 64 + lane;
        #pragma unroll
        for (int j = 0; j < 4; ++j) {
            // j>>1 selects slot within pair (+2048 elements), j&1 half (+512)
            const uint4v* g = src + (j >> 1) * 2048 + (j & 1) * 512;
            gload16((const void*)g, (void*)(dst + j * 512));
        }
    };

    f32x4 C[4] = {};

    auto computePair = [&](int p) {
        const uint4v* bbuf = bb + (p % 3) * 2048 + dtp * 64 + lane;
        #pragma unroll
        for (int sl = 0; sl < 2; ++sl) {
            const int m = p * 2 + sl;
            f32x4 S[4] = {};
            __builtin_amdgcn_s_setprio(1);
            #pragma unroll
            for (int ki = 0; ki < 4; ++ki) {
                bf16x8 bfrag = as_bf(bbuf[sl * 1024 + ki * 256]);
                #pragma unroll
                for (int tf = 0; tf < 4; ++tf)
                    S[tf] = __builtin_amdgcn_mfma_f32_16x16x32_bf16(A[tf][ki], bfrag, S[tf], 0,0,0);
            }
            __builtin_amdgcn_s_setprio(0);
            #pragma unroll
            for (int tf = 0; tf < 4; ++tf) {
                f32x4 af = *(const f32x4*)&attn_f[m * 132 + tg * 64 + tf * 16 + q * 4];
                #pragma unroll
                for (int r = 0; r < 4; ++r)
                    C[tf][r] = fmaf(af[r], S[tf][r], C[tf][r]);
            }
        }
    };

    // ---- Phase 3: 32 slot-pairs, distance-1 counted-vmcnt pipeline
    stage(0, 0);
    for (int p = 0; p < 31; ++p) {
        stage(p + 1, (p + 1) % 3);
        // stage(p) must have landed; stage(p+1)'s 4 loads stay in flight
        // across the barrier (never drain to 0 in the loop).
        asm volatile("s_waitcnt vmcnt(4)" ::: "memory");
        __builtin_amdgcn_s_barrier();
        computePair(p);
    }
    asm volatile("s_waitcnt vmcnt(0)" ::: "memory");
    __builtin_amdgcn_s_barrier();
    computePair(31);

    // ---- Epilogue: direct stores (complete sums; no atomics)
    float* op = out + (size_t)t0 * 128 + dh * 64 + dtp * 16 + l15;
    #pragma unroll
    for (int tf = 0; tf < 4; ++tf)
        #pragma unroll
        for (int r = 0; r < 4; ++r)
            op[(size_t)(tg * 64 + tf * 16 + q * 4 + r) * 128] = C[tf][r];
}

// ---------------------------------------------------------------------------
extern "C" void kernel_launch(void* const* d_in, const int* in_sizes, int n_in,
                              void* d_out, int out_size, void* d_ws, size_t ws_size,
                              hipStream_t stream)
{
    const float* x    = (const float*)d_in[0];   // (4,4096,128)
    const float* keys = (const float*)d_in[1];   // (64,128)
    const float* ops  = (const float*)d_in[2];   // (64,128,128)
    const float* Wq   = (const float*)d_in[3];   // (128,128)
    const float* bq   = (const float*)d_in[4];   // (128,)
    float* out = (float*)d_out;

    char* ws = (char*)d_ws;
    uint4v*   ops_sw = (uint4v*)ws;                        // 2 MB
    ushort_t* kp_sw  = (ushort_t*)(ws + 2097152);          // 16 KB
    float*    cb     = (float*)(ws + 2097152 + 16384);     // 256 B

    prep_kernel<<<576, 256, 0, stream>>>(ops, keys, Wq, bq, ops_sw, kp_sw, cb);
    main_kernel<<<256, 512, 0, stream>>>(x, cb, kp_sw, ops_sw, out);
}